// Round 6
// baseline (439.866 us; speedup 1.0000x reference)
//
#include <hip/hip_runtime.h>

#define IN_CH 128
#define HID 64
#define NEG 0.2f

// ---------------- K1: projections xl = x@W_l.T, xr = x@W_r.T + fused hist --
// 64-node tile, 512 threads (8 waves). Thread = 1 node x 16 ch.
// Wave w: matrix = w>>2, ch-quarter = (w&3)*16.
// W loads FORCED into vector pipe (vzero asm) -> global_load_dwordx4
// broadcast, deep vmcnt pipelining within 128-VGPR budget.
__global__ __launch_bounds__(512, 4) void proj_kernel(
    const float* __restrict__ x, const float* __restrict__ W_l,
    const float* __restrict__ W_r,
    float* __restrict__ xl, float* __restrict__ xr,
    const int* __restrict__ dst, int* __restrict__ deg,
    int nN, int E)
{
    __shared__ float4 x4s[32 * 65];   // 33.3 KB
    int tid = threadIdx.x;
    int nb = blockIdx.x * 64;

    #pragma unroll
    for (int i = 0; i < 4; ++i) {
        int gi = i * 512 + tid;
        int nl = gi >> 5, c4 = gi & 31;
        int node = nb + nl;
        if (node < nN)
            x4s[c4 * 65 + nl] = *(const float4*)(x + (size_t)node * IN_CH + c4 * 4);
    }
    __syncthreads();

    int wid = __builtin_amdgcn_readfirstlane(tid >> 6);   // 0..7, SGPR
    const float* __restrict__ W    = (wid & 4) ? W_r : W_l;
    float* __restrict__       dstv = (wid & 4) ? xr : xl;
    int choff = (wid & 3) * 16;
    int tn = tid & 63;

    // Force vector addressing for W: compiler can't prove vzero==0, so the
    // 16 row-loads per c4 become global_load_dwordx4 (same-addr broadcast),
    // pipelined via vmcnt instead of SGPR-starved s_load chains.
    int vzero;
    asm volatile("v_mov_b32 %0, 0" : "=v"(vzero));
    const float4* Wp = (const float4*)(W + (size_t)choff * IN_CH) + vzero;

    float acc[16];
    #pragma unroll
    for (int c = 0; c < 16; ++c) acc[c] = 0.f;

    #pragma unroll 8
    for (int c4 = 0; c4 < 32; ++c4) {
        float4 xv = x4s[c4 * 65 + tn];
        #pragma unroll
        for (int r4 = 0; r4 < 4; ++r4) {
            float4 w0 = Wp[(r4 * 4 + 0) * 32 + c4];
            float4 w1 = Wp[(r4 * 4 + 1) * 32 + c4];
            float4 w2 = Wp[(r4 * 4 + 2) * 32 + c4];
            float4 w3 = Wp[(r4 * 4 + 3) * 32 + c4];
            acc[r4*4+0] = fmaf(xv.w, w0.w, fmaf(xv.z, w0.z, fmaf(xv.y, w0.y, fmaf(xv.x, w0.x, acc[r4*4+0]))));
            acc[r4*4+1] = fmaf(xv.w, w1.w, fmaf(xv.z, w1.z, fmaf(xv.y, w1.y, fmaf(xv.x, w1.x, acc[r4*4+1]))));
            acc[r4*4+2] = fmaf(xv.w, w2.w, fmaf(xv.z, w2.z, fmaf(xv.y, w2.y, fmaf(xv.x, w2.x, acc[r4*4+2]))));
            acc[r4*4+3] = fmaf(xv.w, w3.w, fmaf(xv.z, w3.z, fmaf(xv.y, w3.y, fmaf(xv.x, w3.x, acc[r4*4+3]))));
        }
    }

    int node = nb + tn;
    if (node < nN) {
        #pragma unroll
        for (int cc = 0; cc < 4; ++cc) {
            float4 o = make_float4(acc[cc*4+0], acc[cc*4+1], acc[cc*4+2], acc[cc*4+3]);
            *(float4*)(dstv + (size_t)node * HID + choff + cc * 4) = o;
        }
    }

    // ---- fused in-degree histogram (grid-stride, int4) ----
    int E4 = E >> 2;
    int gstride = gridDim.x * 512;
    for (int i = blockIdx.x * 512 + tid; i < E4; i += gstride) {
        int4 v = *(const int4*)(dst + i * 4);
        atomicAdd(&deg[v.x], 1);
        atomicAdd(&deg[v.y], 1);
        atomicAdd(&deg[v.z], 1);
        atomicAdd(&deg[v.w], 1);
    }
    if (blockIdx.x == 0 && tid == 0) {
        for (int i = E4 * 4; i < E; ++i) atomicAdd(&deg[dst[i]], 1);
    }
}

// ---------------- K3: exclusive scan, single block, thread-contiguous ------
__global__ __launch_bounds__(1024) void scan_kernel(
    const int* __restrict__ deg, int* __restrict__ row_start,
    int* __restrict__ cursor, int np)
{
    __shared__ int wsum[16];
    int tid = threadIdx.x, lane = tid & 63, w = tid >> 6;
    int base = tid * 52;
    int4 v[13];
    #pragma unroll
    for (int i = 0; i < 13; ++i) v[i] = ((const int4*)(deg + base))[i];
    int run = 0;
    #pragma unroll
    for (int i = 0; i < 13; ++i) {
        int a;
        a = v[i].x; v[i].x = run; run += a;
        a = v[i].y; v[i].y = run; run += a;
        a = v[i].z; v[i].z = run; run += a;
        a = v[i].w; v[i].w = run; run += a;
    }
    int sv = run;
    #pragma unroll
    for (int d = 1; d < 64; d <<= 1) {
        int t = __shfl_up(sv, d, 64);
        if (lane >= d) sv += t;
    }
    if (lane == 63) wsum[w] = sv;
    __syncthreads();
    if (tid < 16) {
        int t = wsum[tid];
        #pragma unroll
        for (int d = 1; d < 16; d <<= 1) {
            int u = __shfl_up(t, d, 64);
            if (tid >= d) t += u;
        }
        wsum[tid] = t;
    }
    __syncthreads();
    int off = (w ? wsum[w - 1] : 0) + (sv - run);
    #pragma unroll
    for (int i = 0; i < 13; ++i) {
        int4 o = make_int4(v[i].x + off, v[i].y + off, v[i].z + off, v[i].w + off);
        ((int4*)(row_start + base))[i] = o;
        ((int4*)(cursor + base))[i] = o;
    }
}

// ---------------- K4: scatter edges into CSR slots (4 edges/thread) --------
__global__ __launch_bounds__(256) void scatter_kernel(
    const int* __restrict__ src, const int* __restrict__ dst,
    int* __restrict__ cursor, int* __restrict__ csr, int E)
{
    int i = (blockIdx.x * 256 + threadIdx.x) * 4;
    if (i + 3 < E) {
        int4 sv = *(const int4*)(src + i);
        int4 dv = *(const int4*)(dst + i);
        int p0 = atomicAdd(&cursor[dv.x], 1); csr[p0] = sv.x;
        int p1 = atomicAdd(&cursor[dv.y], 1); csr[p1] = sv.y;
        int p2 = atomicAdd(&cursor[dv.z], 1); csr[p2] = sv.z;
        int p3 = atomicAdd(&cursor[dv.w], 1); csr[p3] = sv.w;
    } else {
        for (; i < E; ++i) {
            int p = atomicAdd(&cursor[dst[i]], 1);
            csr[p] = src[i];
        }
    }
}

// ---------------- K5: fused attention + aggregation + ELU + linear ----------
// One wave per node; 4 groups x 16 lanes; lane = 4 channels.
// 16 edges per iteration (4 per group): 4 clamped index loads + 4 gathers
// in flight per lane -> 4x MLP.
__global__ __launch_bounds__(256) void gat_main(
    const float* __restrict__ xl, const float* __restrict__ xr,
    const int* __restrict__ row_start, const int* __restrict__ row_end,
    const int* __restrict__ csr,
    const float* __restrict__ att, const float* __restrict__ bias_conv,
    const float* __restrict__ W_lin, const float* __restrict__ b_lin,
    float* __restrict__ out, int nN)
{
    __shared__ float WT[64 * 65];   // WT[c*65+o] = W_lin[o][c], +1 pad
    __shared__ float hbuf[4][64];
    int tid = threadIdx.x;
    for (int idx = tid; idx < 64 * 64; idx += 256) {
        int o = idx >> 6, c = idx & 63;
        WT[c * 65 + o] = W_lin[idx];
    }
    int lane = tid & 63, w = tid >> 6;
    int g = lane >> 4, gl = lane & 15;
    int node = blockIdx.x * 4 + w;
    bool active = node < nN;
    if (active) {
        const float4 att4 = *(const float4*)(att + gl * 4);
        const float4 xr4  = *(const float4*)(xr + (size_t)node * HID + gl * 4);
        float4 acc = make_float4(0.f, 0.f, 0.f, 0.f);
        float denom = 0.f;
        // self loop: group 0 only
        if (g == 0) {
            float4 xs = *(const float4*)(xl + (size_t)node * HID + gl * 4);
            float tx = xs.x + xr4.x, ty = xs.y + xr4.y;
            float tz = xs.z + xr4.z, tw = xs.w + xr4.w;
            float lx = fmaxf(tx, 0.f) + NEG * fminf(tx, 0.f);
            float ly = fmaxf(ty, 0.f) + NEG * fminf(ty, 0.f);
            float lz = fmaxf(tz, 0.f) + NEG * fminf(tz, 0.f);
            float lw = fmaxf(tw, 0.f) + NEG * fminf(tw, 0.f);
            float r = att4.x * lx;
            r = fmaf(att4.y, ly, r); r = fmaf(att4.z, lz, r); r = fmaf(att4.w, lw, r);
            r += __shfl_xor(r, 1, 64);
            r += __shfl_xor(r, 2, 64);
            r += __shfl_xor(r, 4, 64);
            r += __shfl_xor(r, 8, 64);
            float ev = __expf(r);
            denom = ev;
            acc.x = ev * xs.x; acc.y = ev * xs.y;
            acc.z = ev * xs.z; acc.w = ev * xs.w;
        }
        int s0 = row_start[node], e0 = row_end[node];
        int last = e0 - 1;
        for (int base = s0; base < e0; base += 16) {
            int kb = base + g * 4;
            int k0 = (kb     <= last) ? kb     : last;
            int k1 = (kb + 1 <= last) ? kb + 1 : last;
            int k2 = (kb + 2 <= last) ? kb + 2 : last;
            int k3 = (kb + 3 <= last) ? kb + 3 : last;
            int j0 = csr[k0], j1 = csr[k1], j2 = csr[k2], j3 = csr[k3];
            float4 xa = *(const float4*)(xl + (size_t)j0 * HID + gl * 4);
            float4 xb = *(const float4*)(xl + (size_t)j1 * HID + gl * 4);
            float4 xc = *(const float4*)(xl + (size_t)j2 * HID + gl * 4);
            float4 xd = *(const float4*)(xl + (size_t)j3 * HID + gl * 4);

            float t0, t1, t2, t3;
            float ra, rb, rc, rd;
            // edge a
            t0 = xa.x + xr4.x; t1 = xa.y + xr4.y; t2 = xa.z + xr4.z; t3 = xa.w + xr4.w;
            ra =          att4.x * (fmaxf(t0, 0.f) + NEG * fminf(t0, 0.f));
            ra = fmaf(att4.y, fmaxf(t1, 0.f) + NEG * fminf(t1, 0.f), ra);
            ra = fmaf(att4.z, fmaxf(t2, 0.f) + NEG * fminf(t2, 0.f), ra);
            ra = fmaf(att4.w, fmaxf(t3, 0.f) + NEG * fminf(t3, 0.f), ra);
            // edge b
            t0 = xb.x + xr4.x; t1 = xb.y + xr4.y; t2 = xb.z + xr4.z; t3 = xb.w + xr4.w;
            rb =          att4.x * (fmaxf(t0, 0.f) + NEG * fminf(t0, 0.f));
            rb = fmaf(att4.y, fmaxf(t1, 0.f) + NEG * fminf(t1, 0.f), rb);
            rb = fmaf(att4.z, fmaxf(t2, 0.f) + NEG * fminf(t2, 0.f), rb);
            rb = fmaf(att4.w, fmaxf(t3, 0.f) + NEG * fminf(t3, 0.f), rb);
            // edge c
            t0 = xc.x + xr4.x; t1 = xc.y + xr4.y; t2 = xc.z + xr4.z; t3 = xc.w + xr4.w;
            rc =          att4.x * (fmaxf(t0, 0.f) + NEG * fminf(t0, 0.f));
            rc = fmaf(att4.y, fmaxf(t1, 0.f) + NEG * fminf(t1, 0.f), rc);
            rc = fmaf(att4.z, fmaxf(t2, 0.f) + NEG * fminf(t2, 0.f), rc);
            rc = fmaf(att4.w, fmaxf(t3, 0.f) + NEG * fminf(t3, 0.f), rc);
            // edge d
            t0 = xd.x + xr4.x; t1 = xd.y + xr4.y; t2 = xd.z + xr4.z; t3 = xd.w + xr4.w;
            rd =          att4.x * (fmaxf(t0, 0.f) + NEG * fminf(t0, 0.f));
            rd = fmaf(att4.y, fmaxf(t1, 0.f) + NEG * fminf(t1, 0.f), rd);
            rd = fmaf(att4.z, fmaxf(t2, 0.f) + NEG * fminf(t2, 0.f), rd);
            rd = fmaf(att4.w, fmaxf(t3, 0.f) + NEG * fminf(t3, 0.f), rd);

            ra += __shfl_xor(ra, 1, 64); rb += __shfl_xor(rb, 1, 64);
            rc += __shfl_xor(rc, 1, 64); rd += __shfl_xor(rd, 1, 64);
            ra += __shfl_xor(ra, 2, 64); rb += __shfl_xor(rb, 2, 64);
            rc += __shfl_xor(rc, 2, 64); rd += __shfl_xor(rd, 2, 64);
            ra += __shfl_xor(ra, 4, 64); rb += __shfl_xor(rb, 4, 64);
            rc += __shfl_xor(rc, 4, 64); rd += __shfl_xor(rd, 4, 64);
            ra += __shfl_xor(ra, 8, 64); rb += __shfl_xor(rb, 8, 64);
            rc += __shfl_xor(rc, 8, 64); rd += __shfl_xor(rd, 8, 64);

            float ea = (kb     < e0) ? __expf(ra) : 0.f;
            float eb = (kb + 1 < e0) ? __expf(rb) : 0.f;
            float ec = (kb + 2 < e0) ? __expf(rc) : 0.f;
            float ed = (kb + 3 < e0) ? __expf(rd) : 0.f;
            denom += (ea + eb) + (ec + ed);
            acc.x = fmaf(ea, xa.x, acc.x); acc.x = fmaf(eb, xb.x, acc.x);
            acc.x = fmaf(ec, xc.x, acc.x); acc.x = fmaf(ed, xd.x, acc.x);
            acc.y = fmaf(ea, xa.y, acc.y); acc.y = fmaf(eb, xb.y, acc.y);
            acc.y = fmaf(ec, xc.y, acc.y); acc.y = fmaf(ed, xd.y, acc.y);
            acc.z = fmaf(ea, xa.z, acc.z); acc.z = fmaf(eb, xb.z, acc.z);
            acc.z = fmaf(ec, xc.z, acc.z); acc.z = fmaf(ed, xd.z, acc.z);
            acc.w = fmaf(ea, xa.w, acc.w); acc.w = fmaf(eb, xb.w, acc.w);
            acc.w = fmaf(ec, xc.w, acc.w); acc.w = fmaf(ed, xd.w, acc.w);
        }
        denom += __shfl_xor(denom, 16, 64);
        denom += __shfl_xor(denom, 32, 64);
        acc.x += __shfl_xor(acc.x, 16, 64); acc.x += __shfl_xor(acc.x, 32, 64);
        acc.y += __shfl_xor(acc.y, 16, 64); acc.y += __shfl_xor(acc.y, 32, 64);
        acc.z += __shfl_xor(acc.z, 16, 64); acc.z += __shfl_xor(acc.z, 32, 64);
        acc.w += __shfl_xor(acc.w, 16, 64); acc.w += __shfl_xor(acc.w, 32, 64);
        float inv = 1.f / (denom + 1e-16f);
        float4 b4 = *(const float4*)(bias_conv + gl * 4);
        float hx = fmaf(acc.x, inv, b4.x);
        float hy = fmaf(acc.y, inv, b4.y);
        float hz = fmaf(acc.z, inv, b4.z);
        float hw = fmaf(acc.w, inv, b4.w);
        hx = (hx > 0.f) ? hx : (__expf(hx) - 1.f);
        hy = (hy > 0.f) ? hy : (__expf(hy) - 1.f);
        hz = (hz > 0.f) ? hz : (__expf(hz) - 1.f);
        hw = (hw > 0.f) ? hw : (__expf(hw) - 1.f);
        if (g == 0) {
            *(float4*)(&hbuf[w][gl * 4]) = make_float4(hx, hy, hz, hw);
        }
    }
    __syncthreads();
    if (active) {
        float y = b_lin[lane];
        #pragma unroll 8
        for (int c = 0; c < 64; ++c)
            y = fmaf(WT[c * 65 + lane], hbuf[w][c], y);
        out[(size_t)node * 64 + lane] = y;
    }
}

extern "C" void kernel_launch(void* const* d_in, const int* in_sizes, int n_in,
                              void* d_out, int out_size, void* d_ws, size_t ws_size,
                              hipStream_t stream) {
    const float* x      = (const float*)d_in[0];
    const int*   ei     = (const int*)d_in[1];
    // d_in[2] = edge_weight: unused by the reference
    const float* W_l    = (const float*)d_in[3];
    const float* W_r    = (const float*)d_in[4];
    const float* att    = (const float*)d_in[5];
    const float* bias_c = (const float*)d_in[6];
    const float* W_lin  = (const float*)d_in[7];
    const float* b_lin  = (const float*)d_in[8];
    float* out = (float*)d_out;

    int N = in_sizes[0] / IN_CH;
    int E = in_sizes[2];
    const int* srcp = ei;
    const int* dstp = ei + E;

    int NP = 53248;   // 1024 * 52, >= N, int4-aligned per thread

    char* ws = (char*)d_ws;
    float* xl = (float*)ws;
    float* xr = xl + (size_t)N * HID;
    int* deg       = (int*)(xr + (size_t)N * HID);
    int* row_start = deg + NP;
    int* cursor    = row_start + NP;
    int* csr       = cursor + NP;

    hipMemsetAsync(deg, 0, (size_t)NP * sizeof(int), stream);
    proj_kernel<<<(N + 63) / 64, 512, 0, stream>>>(x, W_l, W_r, xl, xr,
                                                   dstp, deg, N, E);
    scan_kernel<<<1, 1024, 0, stream>>>(deg, row_start, cursor, NP);
    scatter_kernel<<<(E / 4 + 255) / 256, 256, 0, stream>>>(srcp, dstp, cursor, csr, E);
    gat_main<<<(N + 3) / 4, 256, 0, stream>>>(xl, xr, row_start, cursor, csr,
                                              att, bias_c, W_lin, b_lin, out, N);
}

// Round 7
// 401.072 us; speedup vs baseline: 1.0967x; 1.0967x over previous
//
#include <hip/hip_runtime.h>

#define IN_CH 128
#define HID 64
#define NEG 0.2f

// ---------------- K1: projections xl = x@W_l.T, xr = x@W_r.T + fused hist --
// W register-resident: wave = one matrix (wid&1), lane = (c4 = 4 rows, kq =
// 32-k slice); wreg[4][8] = 128 VGPR holds the lane's W fragment, loaded once.
// x streamed from global (kq-lanes broadcast-merge in TA); per 4-node batch:
// 32 x-loads, 512 FMA, 32 shfl, 1 coalesced float4 store. No LDS, no barrier.
__global__ __launch_bounds__(256, 2) void proj_kernel(
    const float* __restrict__ x, const float* __restrict__ W_l,
    const float* __restrict__ W_r,
    float* __restrict__ xl, float* __restrict__ xr,
    const int* __restrict__ dst, int* __restrict__ deg,
    int nN, int E)
{
    int tid = threadIdx.x;
    int lane = tid & 63;
    int wid = __builtin_amdgcn_readfirstlane(tid >> 6);   // 0..3
    const float* __restrict__ W    = (wid & 1) ? W_r : W_l;
    float* __restrict__       dstv = (wid & 1) ? xr : xl;
    int wp = blockIdx.x * 2 + (wid >> 1);   // wave-pair (strip) id
    int WP = gridDim.x * 2;

    int c4 = lane >> 2;   // 0..15 -> output rows c4*4 .. c4*4+3
    int kq = lane & 3;    // k slice [kq*32, kq*32+32)

    // preload W fragment (4 rows x 32 k per lane)
    float4 wreg[4][8];
    #pragma unroll
    for (int r = 0; r < 4; ++r) {
        const float* wr = W + (size_t)(c4 * 4 + r) * IN_CH + kq * 32;
        #pragma unroll
        for (int j = 0; j < 8; ++j)
            wreg[r][j] = *(const float4*)(wr + j * 4);
    }

    for (int n0 = wp * 4; n0 < nN; n0 += WP * 4) {   // nN % 4 == 0
        float pr[4][4];
        #pragma unroll
        for (int nn = 0; nn < 4; ++nn) {
            const float* xp = x + (size_t)(n0 + nn) * IN_CH + kq * 32;
            float4 xv[8];
            #pragma unroll
            for (int j = 0; j < 8; ++j) xv[j] = *(const float4*)(xp + j * 4);
            float p0 = 0.f, p1 = 0.f, p2 = 0.f, p3 = 0.f;
            #pragma unroll
            for (int j = 0; j < 8; ++j) {
                float4 xj = xv[j];
                float4 w0 = wreg[0][j], w1 = wreg[1][j];
                float4 w2 = wreg[2][j], w3 = wreg[3][j];
                p0 = fmaf(xj.x, w0.x, p0); p0 = fmaf(xj.y, w0.y, p0);
                p0 = fmaf(xj.z, w0.z, p0); p0 = fmaf(xj.w, w0.w, p0);
                p1 = fmaf(xj.x, w1.x, p1); p1 = fmaf(xj.y, w1.y, p1);
                p1 = fmaf(xj.z, w1.z, p1); p1 = fmaf(xj.w, w1.w, p1);
                p2 = fmaf(xj.x, w2.x, p2); p2 = fmaf(xj.y, w2.y, p2);
                p2 = fmaf(xj.z, w2.z, p2); p2 = fmaf(xj.w, w2.w, p2);
                p3 = fmaf(xj.x, w3.x, p3); p3 = fmaf(xj.y, w3.y, p3);
                p3 = fmaf(xj.z, w3.z, p3); p3 = fmaf(xj.w, w3.w, p3);
            }
            // reduce over kq (lane bits 0-1)
            p0 += __shfl_xor(p0, 1, 64); p0 += __shfl_xor(p0, 2, 64);
            p1 += __shfl_xor(p1, 1, 64); p1 += __shfl_xor(p1, 2, 64);
            p2 += __shfl_xor(p2, 1, 64); p2 += __shfl_xor(p2, 2, 64);
            p3 += __shfl_xor(p3, 1, 64); p3 += __shfl_xor(p3, 2, 64);
            pr[nn][0] = p0; pr[nn][1] = p1; pr[nn][2] = p2; pr[nn][3] = p3;
        }
        // lane kq takes node n0+kq; c4 gives the 4-channel chunk -> coalesced
        float4 o;
        o.x = kq == 0 ? pr[0][0] : kq == 1 ? pr[1][0] : kq == 2 ? pr[2][0] : pr[3][0];
        o.y = kq == 0 ? pr[0][1] : kq == 1 ? pr[1][1] : kq == 2 ? pr[2][1] : pr[3][1];
        o.z = kq == 0 ? pr[0][2] : kq == 1 ? pr[1][2] : kq == 2 ? pr[2][2] : pr[3][2];
        o.w = kq == 0 ? pr[0][3] : kq == 1 ? pr[1][3] : kq == 2 ? pr[2][3] : pr[3][3];
        *(float4*)(dstv + (size_t)(n0 + kq) * HID + c4 * 4) = o;
    }

    // ---- fused in-degree histogram (grid-stride, int4) ----
    int E4 = E >> 2;
    int gstride = gridDim.x * 256;
    for (int i = blockIdx.x * 256 + tid; i < E4; i += gstride) {
        int4 v = *(const int4*)(dst + i * 4);
        atomicAdd(&deg[v.x], 1);
        atomicAdd(&deg[v.y], 1);
        atomicAdd(&deg[v.z], 1);
        atomicAdd(&deg[v.w], 1);
    }
    if (blockIdx.x == 0 && tid == 0) {
        for (int i = E4 * 4; i < E; ++i) atomicAdd(&deg[dst[i]], 1);
    }
}

// ---------------- K3: exclusive scan, single block, thread-contiguous ------
__global__ __launch_bounds__(1024) void scan_kernel(
    const int* __restrict__ deg, int* __restrict__ row_start,
    int* __restrict__ cursor, int np)
{
    __shared__ int wsum[16];
    int tid = threadIdx.x, lane = tid & 63, w = tid >> 6;
    int base = tid * 52;
    int4 v[13];
    #pragma unroll
    for (int i = 0; i < 13; ++i) v[i] = ((const int4*)(deg + base))[i];
    int run = 0;
    #pragma unroll
    for (int i = 0; i < 13; ++i) {
        int a;
        a = v[i].x; v[i].x = run; run += a;
        a = v[i].y; v[i].y = run; run += a;
        a = v[i].z; v[i].z = run; run += a;
        a = v[i].w; v[i].w = run; run += a;
    }
    int sv = run;
    #pragma unroll
    for (int d = 1; d < 64; d <<= 1) {
        int t = __shfl_up(sv, d, 64);
        if (lane >= d) sv += t;
    }
    if (lane == 63) wsum[w] = sv;
    __syncthreads();
    if (tid < 16) {
        int t = wsum[tid];
        #pragma unroll
        for (int d = 1; d < 16; d <<= 1) {
            int u = __shfl_up(t, d, 64);
            if (tid >= d) t += u;
        }
        wsum[tid] = t;
    }
    __syncthreads();
    int off = (w ? wsum[w - 1] : 0) + (sv - run);
    #pragma unroll
    for (int i = 0; i < 13; ++i) {
        int4 o = make_int4(v[i].x + off, v[i].y + off, v[i].z + off, v[i].w + off);
        ((int4*)(row_start + base))[i] = o;
        ((int4*)(cursor + base))[i] = o;
    }
}

// ---------------- K4: scatter edges into CSR slots (4 edges/thread) --------
__global__ __launch_bounds__(256) void scatter_kernel(
    const int* __restrict__ src, const int* __restrict__ dst,
    int* __restrict__ cursor, int* __restrict__ csr, int E)
{
    int i = (blockIdx.x * 256 + threadIdx.x) * 4;
    if (i + 3 < E) {
        int4 sv = *(const int4*)(src + i);
        int4 dv = *(const int4*)(dst + i);
        int p0 = atomicAdd(&cursor[dv.x], 1); csr[p0] = sv.x;
        int p1 = atomicAdd(&cursor[dv.y], 1); csr[p1] = sv.y;
        int p2 = atomicAdd(&cursor[dv.z], 1); csr[p2] = sv.z;
        int p3 = atomicAdd(&cursor[dv.w], 1); csr[p3] = sv.w;
    } else {
        for (; i < E; ++i) {
            int p = atomicAdd(&cursor[dst[i]], 1);
            csr[p] = src[i];
        }
    }
}

// ---------------- K5: fused attention + aggregation + ELU + linear ----------
// One wave per node; 4 groups x 16 lanes; lane = 4 channels.
// 16 edges per iteration (4 per group).
__global__ __launch_bounds__(256) void gat_main(
    const float* __restrict__ xl, const float* __restrict__ xr,
    const int* __restrict__ row_start, const int* __restrict__ row_end,
    const int* __restrict__ csr,
    const float* __restrict__ att, const float* __restrict__ bias_conv,
    const float* __restrict__ W_lin, const float* __restrict__ b_lin,
    float* __restrict__ out, int nN)
{
    __shared__ float WT[64 * 65];   // WT[c*65+o] = W_lin[o][c], +1 pad
    __shared__ float hbuf[4][64];
    int tid = threadIdx.x;
    for (int idx = tid; idx < 64 * 64; idx += 256) {
        int o = idx >> 6, c = idx & 63;
        WT[c * 65 + o] = W_lin[idx];
    }
    int lane = tid & 63, w = tid >> 6;
    int g = lane >> 4, gl = lane & 15;
    int node = blockIdx.x * 4 + w;
    bool active = node < nN;
    if (active) {
        const float4 att4 = *(const float4*)(att + gl * 4);
        const float4 xr4  = *(const float4*)(xr + (size_t)node * HID + gl * 4);
        float4 acc = make_float4(0.f, 0.f, 0.f, 0.f);
        float denom = 0.f;
        // self loop: group 0 only
        if (g == 0) {
            float4 xs = *(const float4*)(xl + (size_t)node * HID + gl * 4);
            float tx = xs.x + xr4.x, ty = xs.y + xr4.y;
            float tz = xs.z + xr4.z, tw = xs.w + xr4.w;
            float lx = fmaxf(tx, 0.f) + NEG * fminf(tx, 0.f);
            float ly = fmaxf(ty, 0.f) + NEG * fminf(ty, 0.f);
            float lz = fmaxf(tz, 0.f) + NEG * fminf(tz, 0.f);
            float lw = fmaxf(tw, 0.f) + NEG * fminf(tw, 0.f);
            float r = att4.x * lx;
            r = fmaf(att4.y, ly, r); r = fmaf(att4.z, lz, r); r = fmaf(att4.w, lw, r);
            r += __shfl_xor(r, 1, 64);
            r += __shfl_xor(r, 2, 64);
            r += __shfl_xor(r, 4, 64);
            r += __shfl_xor(r, 8, 64);
            float ev = __expf(r);
            denom = ev;
            acc.x = ev * xs.x; acc.y = ev * xs.y;
            acc.z = ev * xs.z; acc.w = ev * xs.w;
        }
        int s0 = row_start[node], e0 = row_end[node];
        int last = e0 - 1;
        for (int base = s0; base < e0; base += 16) {
            int kb = base + g * 4;
            int k0 = (kb     <= last) ? kb     : last;
            int k1 = (kb + 1 <= last) ? kb + 1 : last;
            int k2 = (kb + 2 <= last) ? kb + 2 : last;
            int k3 = (kb + 3 <= last) ? kb + 3 : last;
            int j0 = csr[k0], j1 = csr[k1], j2 = csr[k2], j3 = csr[k3];
            float4 xa = *(const float4*)(xl + (size_t)j0 * HID + gl * 4);
            float4 xb = *(const float4*)(xl + (size_t)j1 * HID + gl * 4);
            float4 xc = *(const float4*)(xl + (size_t)j2 * HID + gl * 4);
            float4 xd = *(const float4*)(xl + (size_t)j3 * HID + gl * 4);

            float t0, t1, t2, t3;
            float ra, rb, rc, rd;
            t0 = xa.x + xr4.x; t1 = xa.y + xr4.y; t2 = xa.z + xr4.z; t3 = xa.w + xr4.w;
            ra =          att4.x * (fmaxf(t0, 0.f) + NEG * fminf(t0, 0.f));
            ra = fmaf(att4.y, fmaxf(t1, 0.f) + NEG * fminf(t1, 0.f), ra);
            ra = fmaf(att4.z, fmaxf(t2, 0.f) + NEG * fminf(t2, 0.f), ra);
            ra = fmaf(att4.w, fmaxf(t3, 0.f) + NEG * fminf(t3, 0.f), ra);
            t0 = xb.x + xr4.x; t1 = xb.y + xr4.y; t2 = xb.z + xr4.z; t3 = xb.w + xr4.w;
            rb =          att4.x * (fmaxf(t0, 0.f) + NEG * fminf(t0, 0.f));
            rb = fmaf(att4.y, fmaxf(t1, 0.f) + NEG * fminf(t1, 0.f), rb);
            rb = fmaf(att4.z, fmaxf(t2, 0.f) + NEG * fminf(t2, 0.f), rb);
            rb = fmaf(att4.w, fmaxf(t3, 0.f) + NEG * fminf(t3, 0.f), rb);
            t0 = xc.x + xr4.x; t1 = xc.y + xr4.y; t2 = xc.z + xr4.z; t3 = xc.w + xr4.w;
            rc =          att4.x * (fmaxf(t0, 0.f) + NEG * fminf(t0, 0.f));
            rc = fmaf(att4.y, fmaxf(t1, 0.f) + NEG * fminf(t1, 0.f), rc);
            rc = fmaf(att4.z, fmaxf(t2, 0.f) + NEG * fminf(t2, 0.f), rc);
            rc = fmaf(att4.w, fmaxf(t3, 0.f) + NEG * fminf(t3, 0.f), rc);
            t0 = xd.x + xr4.x; t1 = xd.y + xr4.y; t2 = xd.z + xr4.z; t3 = xd.w + xr4.w;
            rd =          att4.x * (fmaxf(t0, 0.f) + NEG * fminf(t0, 0.f));
            rd = fmaf(att4.y, fmaxf(t1, 0.f) + NEG * fminf(t1, 0.f), rd);
            rd = fmaf(att4.z, fmaxf(t2, 0.f) + NEG * fminf(t2, 0.f), rd);
            rd = fmaf(att4.w, fmaxf(t3, 0.f) + NEG * fminf(t3, 0.f), rd);

            ra += __shfl_xor(ra, 1, 64); rb += __shfl_xor(rb, 1, 64);
            rc += __shfl_xor(rc, 1, 64); rd += __shfl_xor(rd, 1, 64);
            ra += __shfl_xor(ra, 2, 64); rb += __shfl_xor(rb, 2, 64);
            rc += __shfl_xor(rc, 2, 64); rd += __shfl_xor(rd, 2, 64);
            ra += __shfl_xor(ra, 4, 64); rb += __shfl_xor(rb, 4, 64);
            rc += __shfl_xor(rc, 4, 64); rd += __shfl_xor(rd, 4, 64);
            ra += __shfl_xor(ra, 8, 64); rb += __shfl_xor(rb, 8, 64);
            rc += __shfl_xor(rc, 8, 64); rd += __shfl_xor(rd, 8, 64);

            float ea = (kb     < e0) ? __expf(ra) : 0.f;
            float eb = (kb + 1 < e0) ? __expf(rb) : 0.f;
            float ec = (kb + 2 < e0) ? __expf(rc) : 0.f;
            float ed = (kb + 3 < e0) ? __expf(rd) : 0.f;
            denom += (ea + eb) + (ec + ed);
            acc.x = fmaf(ea, xa.x, acc.x); acc.x = fmaf(eb, xb.x, acc.x);
            acc.x = fmaf(ec, xc.x, acc.x); acc.x = fmaf(ed, xd.x, acc.x);
            acc.y = fmaf(ea, xa.y, acc.y); acc.y = fmaf(eb, xb.y, acc.y);
            acc.y = fmaf(ec, xc.y, acc.y); acc.y = fmaf(ed, xd.y, acc.y);
            acc.z = fmaf(ea, xa.z, acc.z); acc.z = fmaf(eb, xb.z, acc.z);
            acc.z = fmaf(ec, xc.z, acc.z); acc.z = fmaf(ed, xd.z, acc.z);
            acc.w = fmaf(ea, xa.w, acc.w); acc.w = fmaf(eb, xb.w, acc.w);
            acc.w = fmaf(ec, xc.w, acc.w); acc.w = fmaf(ed, xd.w, acc.w);
        }
        denom += __shfl_xor(denom, 16, 64);
        denom += __shfl_xor(denom, 32, 64);
        acc.x += __shfl_xor(acc.x, 16, 64); acc.x += __shfl_xor(acc.x, 32, 64);
        acc.y += __shfl_xor(acc.y, 16, 64); acc.y += __shfl_xor(acc.y, 32, 64);
        acc.z += __shfl_xor(acc.z, 16, 64); acc.z += __shfl_xor(acc.z, 32, 64);
        acc.w += __shfl_xor(acc.w, 16, 64); acc.w += __shfl_xor(acc.w, 32, 64);
        float inv = 1.f / (denom + 1e-16f);
        float4 b4 = *(const float4*)(bias_conv + gl * 4);
        float hx = fmaf(acc.x, inv, b4.x);
        float hy = fmaf(acc.y, inv, b4.y);
        float hz = fmaf(acc.z, inv, b4.z);
        float hw = fmaf(acc.w, inv, b4.w);
        hx = (hx > 0.f) ? hx : (__expf(hx) - 1.f);
        hy = (hy > 0.f) ? hy : (__expf(hy) - 1.f);
        hz = (hz > 0.f) ? hz : (__expf(hz) - 1.f);
        hw = (hw > 0.f) ? hw : (__expf(hw) - 1.f);
        if (g == 0) {
            *(float4*)(&hbuf[w][gl * 4]) = make_float4(hx, hy, hz, hw);
        }
    }
    __syncthreads();
    if (active) {
        float y = b_lin[lane];
        #pragma unroll 8
        for (int c = 0; c < 64; ++c)
            y = fmaf(WT[c * 65 + lane], hbuf[w][c], y);
        out[(size_t)node * 64 + lane] = y;
    }
}

extern "C" void kernel_launch(void* const* d_in, const int* in_sizes, int n_in,
                              void* d_out, int out_size, void* d_ws, size_t ws_size,
                              hipStream_t stream) {
    const float* x      = (const float*)d_in[0];
    const int*   ei     = (const int*)d_in[1];
    // d_in[2] = edge_weight: unused by the reference
    const float* W_l    = (const float*)d_in[3];
    const float* W_r    = (const float*)d_in[4];
    const float* att    = (const float*)d_in[5];
    const float* bias_c = (const float*)d_in[6];
    const float* W_lin  = (const float*)d_in[7];
    const float* b_lin  = (const float*)d_in[8];
    float* out = (float*)d_out;

    int N = in_sizes[0] / IN_CH;
    int E = in_sizes[2];
    const int* srcp = ei;
    const int* dstp = ei + E;

    int NP = 53248;   // 1024 * 52, >= N, int4-aligned per thread

    char* ws = (char*)d_ws;
    float* xl = (float*)ws;
    float* xr = xl + (size_t)N * HID;
    int* deg       = (int*)(xr + (size_t)N * HID);
    int* row_start = deg + NP;
    int* cursor    = row_start + NP;
    int* csr       = cursor + NP;

    hipMemsetAsync(deg, 0, (size_t)NP * sizeof(int), stream);
    proj_kernel<<<512, 256, 0, stream>>>(x, W_l, W_r, xl, xr, dstp, deg, N, E);
    scan_kernel<<<1, 1024, 0, stream>>>(deg, row_start, cursor, NP);
    scatter_kernel<<<(E / 4 + 255) / 256, 256, 0, stream>>>(srcp, dstp, cursor, csr, E);
    gat_main<<<(N + 3) / 4, 256, 0, stream>>>(xl, xr, row_start, cursor, csr,
                                              att, bias_c, W_lin, b_lin, out, N);
}

// Round 8
// 337.106 us; speedup vs baseline: 1.3048x; 1.1897x over previous
//
#include <hip/hip_runtime.h>

#define IN_CH 128
#define HID 64
#define NEG 0.2f

__device__ __forceinline__ unsigned short f2bf(float f) {
    unsigned u = __float_as_uint(f);
    u += 0x7fffu + ((u >> 16) & 1u);   // RNE
    return (unsigned short)(u >> 16);
}
__device__ __forceinline__ float bf2f(unsigned short h) {
    return __uint_as_float((unsigned)h << 16);
}

// ---------------- K1: projections xl(bf16) = x@W_l.T, xr(f32) = x@W_r.T ----
// R5 structure (best measured): 64-node tile, 512 threads, thread = 1 node x
// 16 ch, W via wave-uniform s_loads, LDS only for x. Fused in-degree hist.
__global__ __launch_bounds__(512, 6) void proj_kernel(
    const float* __restrict__ x, const float* __restrict__ W_l,
    const float* __restrict__ W_r,
    unsigned short* __restrict__ xlb, float* __restrict__ xr,
    const int* __restrict__ dst, int* __restrict__ deg,
    int nN, int E)
{
    __shared__ float4 x4s[32 * 65];   // 33.3 KB
    int tid = threadIdx.x;
    int nb = blockIdx.x * 64;

    #pragma unroll
    for (int i = 0; i < 4; ++i) {
        int gi = i * 512 + tid;
        int nl = gi >> 5, c4 = gi & 31;
        int node = nb + nl;
        if (node < nN)
            x4s[c4 * 65 + nl] = *(const float4*)(x + (size_t)node * IN_CH + c4 * 4);
    }
    __syncthreads();

    int wid = __builtin_amdgcn_readfirstlane(tid >> 6);   // 0..7, SGPR
    const float* __restrict__ W = (wid & 4) ? W_r : W_l;
    int choff = (wid & 3) * 16;
    int tn = tid & 63;

    float acc[16];
    #pragma unroll
    for (int c = 0; c < 16; ++c) acc[c] = 0.f;

    #pragma unroll 2
    for (int c4 = 0; c4 < 32; ++c4) {
        float4 xv = x4s[c4 * 65 + tn];
        #pragma unroll
        for (int cc = 0; cc < 4; ++cc) {
            const float* wrow = W + (size_t)(choff + cc * 4) * IN_CH + c4 * 4;
            float4 w0 = *(const float4*)(wrow);
            float4 w1 = *(const float4*)(wrow + IN_CH);
            float4 w2 = *(const float4*)(wrow + 2 * IN_CH);
            float4 w3 = *(const float4*)(wrow + 3 * IN_CH);
            acc[cc*4+0] = fmaf(xv.w, w0.w, fmaf(xv.z, w0.z, fmaf(xv.y, w0.y, fmaf(xv.x, w0.x, acc[cc*4+0]))));
            acc[cc*4+1] = fmaf(xv.w, w1.w, fmaf(xv.z, w1.z, fmaf(xv.y, w1.y, fmaf(xv.x, w1.x, acc[cc*4+1]))));
            acc[cc*4+2] = fmaf(xv.w, w2.w, fmaf(xv.z, w2.z, fmaf(xv.y, w2.y, fmaf(xv.x, w2.x, acc[cc*4+2]))));
            acc[cc*4+3] = fmaf(xv.w, w3.w, fmaf(xv.z, w3.z, fmaf(xv.y, w3.y, fmaf(xv.x, w3.x, acc[cc*4+3]))));
        }
    }

    int node = nb + tn;
    if (node < nN) {
        if (wid & 4) {
            // xr: fp32
            #pragma unroll
            for (int cc = 0; cc < 4; ++cc) {
                float4 o = make_float4(acc[cc*4+0], acc[cc*4+1], acc[cc*4+2], acc[cc*4+3]);
                *(float4*)(xr + (size_t)node * HID + choff + cc * 4) = o;
            }
        } else {
            // xl: bf16 (RNE), 16 values -> two uint4 stores
            uint4 p0, p1;
            p0.x = (unsigned)f2bf(acc[0])  | ((unsigned)f2bf(acc[1])  << 16);
            p0.y = (unsigned)f2bf(acc[2])  | ((unsigned)f2bf(acc[3])  << 16);
            p0.z = (unsigned)f2bf(acc[4])  | ((unsigned)f2bf(acc[5])  << 16);
            p0.w = (unsigned)f2bf(acc[6])  | ((unsigned)f2bf(acc[7])  << 16);
            p1.x = (unsigned)f2bf(acc[8])  | ((unsigned)f2bf(acc[9])  << 16);
            p1.y = (unsigned)f2bf(acc[10]) | ((unsigned)f2bf(acc[11]) << 16);
            p1.z = (unsigned)f2bf(acc[12]) | ((unsigned)f2bf(acc[13]) << 16);
            p1.w = (unsigned)f2bf(acc[14]) | ((unsigned)f2bf(acc[15]) << 16);
            *(uint4*)(xlb + (size_t)node * HID + choff)     = p0;
            *(uint4*)(xlb + (size_t)node * HID + choff + 8) = p1;
        }
    }

    // ---- fused in-degree histogram (grid-stride, int4) ----
    int E4 = E >> 2;
    int gstride = gridDim.x * 512;
    for (int i = blockIdx.x * 512 + tid; i < E4; i += gstride) {
        int4 v = *(const int4*)(dst + i * 4);
        atomicAdd(&deg[v.x], 1);
        atomicAdd(&deg[v.y], 1);
        atomicAdd(&deg[v.z], 1);
        atomicAdd(&deg[v.w], 1);
    }
    if (blockIdx.x == 0 && tid == 0) {
        for (int i = E4 * 4; i < E; ++i) atomicAdd(&deg[dst[i]], 1);
    }
}

// ---------------- K3: exclusive scan, single block, thread-contiguous ------
__global__ __launch_bounds__(1024) void scan_kernel(
    const int* __restrict__ deg, int* __restrict__ row_start,
    int* __restrict__ cursor, int np)
{
    __shared__ int wsum[16];
    int tid = threadIdx.x, lane = tid & 63, w = tid >> 6;
    int base = tid * 52;
    int4 v[13];
    #pragma unroll
    for (int i = 0; i < 13; ++i) v[i] = ((const int4*)(deg + base))[i];
    int run = 0;
    #pragma unroll
    for (int i = 0; i < 13; ++i) {
        int a;
        a = v[i].x; v[i].x = run; run += a;
        a = v[i].y; v[i].y = run; run += a;
        a = v[i].z; v[i].z = run; run += a;
        a = v[i].w; v[i].w = run; run += a;
    }
    int sv = run;
    #pragma unroll
    for (int d = 1; d < 64; d <<= 1) {
        int t = __shfl_up(sv, d, 64);
        if (lane >= d) sv += t;
    }
    if (lane == 63) wsum[w] = sv;
    __syncthreads();
    if (tid < 16) {
        int t = wsum[tid];
        #pragma unroll
        for (int d = 1; d < 16; d <<= 1) {
            int u = __shfl_up(t, d, 64);
            if (tid >= d) t += u;
        }
        wsum[tid] = t;
    }
    __syncthreads();
    int off = (w ? wsum[w - 1] : 0) + (sv - run);
    #pragma unroll
    for (int i = 0; i < 13; ++i) {
        int4 o = make_int4(v[i].x + off, v[i].y + off, v[i].z + off, v[i].w + off);
        ((int4*)(row_start + base))[i] = o;
        ((int4*)(cursor + base))[i] = o;
    }
}

// ---------------- K4: scatter edges into CSR slots (4 edges/thread) --------
__global__ __launch_bounds__(256) void scatter_kernel(
    const int* __restrict__ src, const int* __restrict__ dst,
    int* __restrict__ cursor, int* __restrict__ csr, int E)
{
    int i = (blockIdx.x * 256 + threadIdx.x) * 4;
    if (i + 3 < E) {
        int4 sv = *(const int4*)(src + i);
        int4 dv = *(const int4*)(dst + i);
        int p0 = atomicAdd(&cursor[dv.x], 1); csr[p0] = sv.x;
        int p1 = atomicAdd(&cursor[dv.y], 1); csr[p1] = sv.y;
        int p2 = atomicAdd(&cursor[dv.z], 1); csr[p2] = sv.z;
        int p3 = atomicAdd(&cursor[dv.w], 1); csr[p3] = sv.w;
    } else {
        for (; i < E; ++i) {
            int p = atomicAdd(&cursor[dst[i]], 1);
            csr[p] = src[i];
        }
    }
}

// ---------------- K5: fused attention + aggregation + ELU + linear ----------
// One wave per node; 4 groups x 16 lanes; lane = 4 channels; 16 edges/iter.
// xl gathers are bf16 (8B/lane) -> half the gather traffic of fp32.
__global__ __launch_bounds__(256) void gat_main(
    const unsigned short* __restrict__ xlb, const float* __restrict__ xr,
    const int* __restrict__ row_start, const int* __restrict__ row_end,
    const int* __restrict__ csr,
    const float* __restrict__ att, const float* __restrict__ bias_conv,
    const float* __restrict__ W_lin, const float* __restrict__ b_lin,
    float* __restrict__ out, int nN)
{
    __shared__ float WT[64 * 65];   // WT[c*65+o] = W_lin[o][c], +1 pad
    __shared__ float hbuf[4][64];
    int tid = threadIdx.x;
    for (int idx = tid; idx < 64 * 64; idx += 256) {
        int o = idx >> 6, c = idx & 63;
        WT[c * 65 + o] = W_lin[idx];
    }
    int lane = tid & 63, w = tid >> 6;
    int g = lane >> 4, gl = lane & 15;
    int node = blockIdx.x * 4 + w;
    bool active = node < nN;
    if (active) {
        const float4 att4 = *(const float4*)(att + gl * 4);
        const float4 xr4  = *(const float4*)(xr + (size_t)node * HID + gl * 4);
        float4 acc = make_float4(0.f, 0.f, 0.f, 0.f);
        float denom = 0.f;
        // self loop: group 0 only
        if (g == 0) {
            ushort4 us = *(const ushort4*)(xlb + (size_t)node * HID + gl * 4);
            float xsx = bf2f(us.x), xsy = bf2f(us.y), xsz = bf2f(us.z), xsw = bf2f(us.w);
            float tx = xsx + xr4.x, ty = xsy + xr4.y;
            float tz = xsz + xr4.z, tw = xsw + xr4.w;
            float r =          att4.x * (fmaxf(tx, 0.f) + NEG * fminf(tx, 0.f));
            r = fmaf(att4.y, fmaxf(ty, 0.f) + NEG * fminf(ty, 0.f), r);
            r = fmaf(att4.z, fmaxf(tz, 0.f) + NEG * fminf(tz, 0.f), r);
            r = fmaf(att4.w, fmaxf(tw, 0.f) + NEG * fminf(tw, 0.f), r);
            r += __shfl_xor(r, 1, 64);
            r += __shfl_xor(r, 2, 64);
            r += __shfl_xor(r, 4, 64);
            r += __shfl_xor(r, 8, 64);
            float ev = __expf(r);
            denom = ev;
            acc.x = ev * xsx; acc.y = ev * xsy;
            acc.z = ev * xsz; acc.w = ev * xsw;
        }
        int s0 = row_start[node], e0 = row_end[node];
        int last = e0 - 1;
        for (int base = s0; base < e0; base += 16) {
            int kb = base + g * 4;
            int k0 = (kb     <= last) ? kb     : last;
            int k1 = (kb + 1 <= last) ? kb + 1 : last;
            int k2 = (kb + 2 <= last) ? kb + 2 : last;
            int k3 = (kb + 3 <= last) ? kb + 3 : last;
            int j0 = csr[k0], j1 = csr[k1], j2 = csr[k2], j3 = csr[k3];
            ushort4 ua = *(const ushort4*)(xlb + (size_t)j0 * HID + gl * 4);
            ushort4 ub = *(const ushort4*)(xlb + (size_t)j1 * HID + gl * 4);
            ushort4 uc = *(const ushort4*)(xlb + (size_t)j2 * HID + gl * 4);
            ushort4 ud = *(const ushort4*)(xlb + (size_t)j3 * HID + gl * 4);
            float xax = bf2f(ua.x), xay = bf2f(ua.y), xaz = bf2f(ua.z), xaw = bf2f(ua.w);
            float xbx = bf2f(ub.x), xby = bf2f(ub.y), xbz = bf2f(ub.z), xbw = bf2f(ub.w);
            float xcx = bf2f(uc.x), xcy = bf2f(uc.y), xcz = bf2f(uc.z), xcw = bf2f(uc.w);
            float xdx = bf2f(ud.x), xdy = bf2f(ud.y), xdz = bf2f(ud.z), xdw = bf2f(ud.w);

            float t0, t1, t2, t3;
            float ra, rb, rc, rd;
            t0 = xax + xr4.x; t1 = xay + xr4.y; t2 = xaz + xr4.z; t3 = xaw + xr4.w;
            ra =          att4.x * (fmaxf(t0, 0.f) + NEG * fminf(t0, 0.f));
            ra = fmaf(att4.y, fmaxf(t1, 0.f) + NEG * fminf(t1, 0.f), ra);
            ra = fmaf(att4.z, fmaxf(t2, 0.f) + NEG * fminf(t2, 0.f), ra);
            ra = fmaf(att4.w, fmaxf(t3, 0.f) + NEG * fminf(t3, 0.f), ra);
            t0 = xbx + xr4.x; t1 = xby + xr4.y; t2 = xbz + xr4.z; t3 = xbw + xr4.w;
            rb =          att4.x * (fmaxf(t0, 0.f) + NEG * fminf(t0, 0.f));
            rb = fmaf(att4.y, fmaxf(t1, 0.f) + NEG * fminf(t1, 0.f), rb);
            rb = fmaf(att4.z, fmaxf(t2, 0.f) + NEG * fminf(t2, 0.f), rb);
            rb = fmaf(att4.w, fmaxf(t3, 0.f) + NEG * fminf(t3, 0.f), rb);
            t0 = xcx + xr4.x; t1 = xcy + xr4.y; t2 = xcz + xr4.z; t3 = xcw + xr4.w;
            rc =          att4.x * (fmaxf(t0, 0.f) + NEG * fminf(t0, 0.f));
            rc = fmaf(att4.y, fmaxf(t1, 0.f) + NEG * fminf(t1, 0.f), rc);
            rc = fmaf(att4.z, fmaxf(t2, 0.f) + NEG * fminf(t2, 0.f), rc);
            rc = fmaf(att4.w, fmaxf(t3, 0.f) + NEG * fminf(t3, 0.f), rc);
            t0 = xdx + xr4.x; t1 = xdy + xr4.y; t2 = xdz + xr4.z; t3 = xdw + xr4.w;
            rd =          att4.x * (fmaxf(t0, 0.f) + NEG * fminf(t0, 0.f));
            rd = fmaf(att4.y, fmaxf(t1, 0.f) + NEG * fminf(t1, 0.f), rd);
            rd = fmaf(att4.z, fmaxf(t2, 0.f) + NEG * fminf(t2, 0.f), rd);
            rd = fmaf(att4.w, fmaxf(t3, 0.f) + NEG * fminf(t3, 0.f), rd);

            ra += __shfl_xor(ra, 1, 64); rb += __shfl_xor(rb, 1, 64);
            rc += __shfl_xor(rc, 1, 64); rd += __shfl_xor(rd, 1, 64);
            ra += __shfl_xor(ra, 2, 64); rb += __shfl_xor(rb, 2, 64);
            rc += __shfl_xor(rc, 2, 64); rd += __shfl_xor(rd, 2, 64);
            ra += __shfl_xor(ra, 4, 64); rb += __shfl_xor(rb, 4, 64);
            rc += __shfl_xor(rc, 4, 64); rd += __shfl_xor(rd, 4, 64);
            ra += __shfl_xor(ra, 8, 64); rb += __shfl_xor(rb, 8, 64);
            rc += __shfl_xor(rc, 8, 64); rd += __shfl_xor(rd, 8, 64);

            float ea = (kb     < e0) ? __expf(ra) : 0.f;
            float eb = (kb + 1 < e0) ? __expf(rb) : 0.f;
            float ec = (kb + 2 < e0) ? __expf(rc) : 0.f;
            float ed = (kb + 3 < e0) ? __expf(rd) : 0.f;
            denom += (ea + eb) + (ec + ed);
            acc.x = fmaf(ea, xax, acc.x); acc.x = fmaf(eb, xbx, acc.x);
            acc.x = fmaf(ec, xcx, acc.x); acc.x = fmaf(ed, xdx, acc.x);
            acc.y = fmaf(ea, xay, acc.y); acc.y = fmaf(eb, xby, acc.y);
            acc.y = fmaf(ec, xcy, acc.y); acc.y = fmaf(ed, xdy, acc.y);
            acc.z = fmaf(ea, xaz, acc.z); acc.z = fmaf(eb, xbz, acc.z);
            acc.z = fmaf(ec, xcz, acc.z); acc.z = fmaf(ed, xdz, acc.z);
            acc.w = fmaf(ea, xaw, acc.w); acc.w = fmaf(eb, xbw, acc.w);
            acc.w = fmaf(ec, xcw, acc.w); acc.w = fmaf(ed, xdw, acc.w);
        }
        denom += __shfl_xor(denom, 16, 64);
        denom += __shfl_xor(denom, 32, 64);
        acc.x += __shfl_xor(acc.x, 16, 64); acc.x += __shfl_xor(acc.x, 32, 64);
        acc.y += __shfl_xor(acc.y, 16, 64); acc.y += __shfl_xor(acc.y, 32, 64);
        acc.z += __shfl_xor(acc.z, 16, 64); acc.z += __shfl_xor(acc.z, 32, 64);
        acc.w += __shfl_xor(acc.w, 16, 64); acc.w += __shfl_xor(acc.w, 32, 64);
        float inv = 1.f / (denom + 1e-16f);
        float4 b4 = *(const float4*)(bias_conv + gl * 4);
        float hx = fmaf(acc.x, inv, b4.x);
        float hy = fmaf(acc.y, inv, b4.y);
        float hz = fmaf(acc.z, inv, b4.z);
        float hw = fmaf(acc.w, inv, b4.w);
        hx = (hx > 0.f) ? hx : (__expf(hx) - 1.f);
        hy = (hy > 0.f) ? hy : (__expf(hy) - 1.f);
        hz = (hz > 0.f) ? hz : (__expf(hz) - 1.f);
        hw = (hw > 0.f) ? hw : (__expf(hw) - 1.f);
        if (g == 0) {
            *(float4*)(&hbuf[w][gl * 4]) = make_float4(hx, hy, hz, hw);
        }
    }
    __syncthreads();
    if (active) {
        float y = b_lin[lane];
        #pragma unroll 8
        for (int c = 0; c < 64; ++c)
            y = fmaf(WT[c * 65 + lane], hbuf[w][c], y);
        out[(size_t)node * 64 + lane] = y;
    }
}

extern "C" void kernel_launch(void* const* d_in, const int* in_sizes, int n_in,
                              void* d_out, int out_size, void* d_ws, size_t ws_size,
                              hipStream_t stream) {
    const float* x      = (const float*)d_in[0];
    const int*   ei     = (const int*)d_in[1];
    // d_in[2] = edge_weight: unused by the reference
    const float* W_l    = (const float*)d_in[3];
    const float* W_r    = (const float*)d_in[4];
    const float* att    = (const float*)d_in[5];
    const float* bias_c = (const float*)d_in[6];
    const float* W_lin  = (const float*)d_in[7];
    const float* b_lin  = (const float*)d_in[8];
    float* out = (float*)d_out;

    int N = in_sizes[0] / IN_CH;
    int E = in_sizes[2];
    const int* srcp = ei;
    const int* dstp = ei + E;

    int NP = 53248;   // 1024 * 52, >= N, int4-aligned per thread

    char* ws = (char*)d_ws;
    float* xr = (float*)ws;                                   // N*64 f32
    unsigned short* xlb = (unsigned short*)(xr + (size_t)N * HID);  // N*64 bf16
    int* deg       = (int*)(xlb + (size_t)N * HID);
    int* row_start = deg + NP;
    int* cursor    = row_start + NP;
    int* csr       = cursor + NP;

    hipMemsetAsync(deg, 0, (size_t)NP * sizeof(int), stream);
    proj_kernel<<<(N + 63) / 64, 512, 0, stream>>>(x, W_l, W_r, xlb, xr,
                                                   dstp, deg, N, E);
    scan_kernel<<<1, 1024, 0, stream>>>(deg, row_start, cursor, NP);
    scatter_kernel<<<(E / 4 + 255) / 256, 256, 0, stream>>>(srcp, dstp, cursor, csr, E);
    gat_main<<<(N + 3) / 4, 256, 0, stream>>>(xlb, xr, row_start, cursor, csr,
                                              att, bias_c, W_lin, b_lin, out, N);
}

// Round 9
// 312.272 us; speedup vs baseline: 1.4086x; 1.0795x over previous
//
#include <hip/hip_runtime.h>

#define IN_CH 128
#define HID 64
#define NEG 0.2f

typedef short bf16x8 __attribute__((ext_vector_type(8)));
typedef float f32x4  __attribute__((ext_vector_type(4)));

__device__ __forceinline__ unsigned short f2bf(float f) {
    unsigned u = __float_as_uint(f);
    u += 0x7fffu + ((u >> 16) & 1u);   // RNE
    return (unsigned short)(u >> 16);
}
__device__ __forceinline__ float bf2f(unsigned short h) {
    return __uint_as_float((unsigned)h << 16);
}

// ---------------- K1: MFMA projections + fused in-degree hist ----------------
// Block = 64-node tile, 512 thr = 8 waves = {W_l,W_r} x 4 ch-tiles(16).
// x staged to LDS as split-bf16 (hi + lo residual); W fragments likewise in
// VGPRs (8 frags x 16B). GEMM via mfma_f32_16x16x32_bf16, 3 mfma per tile
// (AhBh + AhBl + AlBh) -> fp32-grade accuracy. Memory-bound by construction.
__global__ __launch_bounds__(512, 4) void proj_kernel(
    const float* __restrict__ x, const float* __restrict__ W_l,
    const float* __restrict__ W_r,
    unsigned short* __restrict__ xlb, float* __restrict__ xr,
    const int* __restrict__ dst, int* __restrict__ deg,
    int nN, int E)
{
    __shared__ unsigned short A_hi[64 * 136];   // 17.4 KB, +8 pad per row
    __shared__ unsigned short A_lo[64 * 136];   // 17.4 KB
    int tid = threadIdx.x;
    int nb = blockIdx.x * 64;
    int lane = tid & 63;
    int wid = __builtin_amdgcn_readfirstlane(tid >> 6);   // 0..7
    int mat = wid >> 2;          // 0: W_l -> xlb, 1: W_r -> xr
    int ct  = (wid & 3) * 16;    // ch-tile base
    int n = lane & 15, quad = lane >> 4;

    // ---- preload W fragments (this wave's 16 out-ch), split hi/lo ----
    const float* __restrict__ W = mat ? W_r : W_l;
    bf16x8 Bh[4], Bl[4];
    #pragma unroll
    for (int s = 0; s < 4; ++s) {
        const float* wr = W + (size_t)(ct + n) * IN_CH + s * 32 + quad * 8;
        float4 w0 = *(const float4*)(wr);
        float4 w1 = *(const float4*)(wr + 4);
        float wf[8] = {w0.x, w0.y, w0.z, w0.w, w1.x, w1.y, w1.z, w1.w};
        #pragma unroll
        for (int j = 0; j < 8; ++j) {
            unsigned short h = f2bf(wf[j]);
            Bh[s][j] = (short)h;
            Bl[s][j] = (short)f2bf(wf[j] - bf2f(h));
        }
    }

    // ---- stage x tile (64 x 128) as split-bf16 into LDS ----
    #pragma unroll
    for (int it = 0; it < 2; ++it) {
        int gi = it * 512 + tid;          // 0..1023
        int row = gi >> 4, c8 = gi & 15;  // row 0..63, 8-elem chunk 0..15
        int node = nb + row;
        uint4 hi = make_uint4(0, 0, 0, 0), lo = make_uint4(0, 0, 0, 0);
        if (node < nN) {
            const float* xp = x + (size_t)node * IN_CH + c8 * 8;
            float4 f0 = *(const float4*)(xp);
            float4 f1 = *(const float4*)(xp + 4);
            float xf[8] = {f0.x, f0.y, f0.z, f0.w, f1.x, f1.y, f1.z, f1.w};
            unsigned hh[8], ll[8];
            #pragma unroll
            for (int j = 0; j < 8; ++j) {
                unsigned short h = f2bf(xf[j]);
                hh[j] = h;
                ll[j] = f2bf(xf[j] - bf2f(h));
            }
            hi = make_uint4(hh[0] | (hh[1] << 16), hh[2] | (hh[3] << 16),
                            hh[4] | (hh[5] << 16), hh[6] | (hh[7] << 16));
            lo = make_uint4(ll[0] | (ll[1] << 16), ll[2] | (ll[3] << 16),
                            ll[4] | (ll[5] << 16), ll[6] | (ll[7] << 16));
        }
        *(uint4*)(&A_hi[row * 136 + c8 * 8]) = hi;
        *(uint4*)(&A_lo[row * 136 + c8 * 8]) = lo;
    }
    __syncthreads();

    // ---- MFMA main: 4 m-tiles x 4 k-steps x 3 mfma ----
    #pragma unroll
    for (int mt = 0; mt < 4; ++mt) {
        f32x4 d = {0.f, 0.f, 0.f, 0.f};
        int arow = (mt * 16 + n) * 136 + quad * 8;
        #pragma unroll
        for (int s = 0; s < 4; ++s) {
            bf16x8 ah = *(const bf16x8*)(&A_hi[arow + s * 32]);
            bf16x8 al = *(const bf16x8*)(&A_lo[arow + s * 32]);
            d = __builtin_amdgcn_mfma_f32_16x16x32_bf16(ah, Bh[s], d, 0, 0, 0);
            d = __builtin_amdgcn_mfma_f32_16x16x32_bf16(ah, Bl[s], d, 0, 0, 0);
            d = __builtin_amdgcn_mfma_f32_16x16x32_bf16(al, Bh[s], d, 0, 0, 0);
        }
        // D: col = lane&15 -> out-ch (ct+n), row = quad*4+r -> node in tile
        #pragma unroll
        for (int r = 0; r < 4; ++r) {
            int node = nb + mt * 16 + quad * 4 + r;
            if (node < nN) {
                if (mat)
                    xr[(size_t)node * HID + ct + n] = d[r];
                else
                    xlb[(size_t)node * HID + ct + n] = f2bf(d[r]);
            }
        }
    }

    // ---- fused in-degree histogram (grid-stride, int4) ----
    int E4 = E >> 2;
    int gstride = gridDim.x * 512;
    for (int i = blockIdx.x * 512 + tid; i < E4; i += gstride) {
        int4 v = *(const int4*)(dst + i * 4);
        atomicAdd(&deg[v.x], 1);
        atomicAdd(&deg[v.y], 1);
        atomicAdd(&deg[v.z], 1);
        atomicAdd(&deg[v.w], 1);
    }
    if (blockIdx.x == 0 && tid == 0) {
        for (int i = E4 * 4; i < E; ++i) atomicAdd(&deg[dst[i]], 1);
    }
}

// ---------------- K3: exclusive scan, single block, thread-contiguous ------
__global__ __launch_bounds__(1024) void scan_kernel(
    const int* __restrict__ deg, int* __restrict__ row_start,
    int* __restrict__ cursor, int np)
{
    __shared__ int wsum[16];
    int tid = threadIdx.x, lane = tid & 63, w = tid >> 6;
    int base = tid * 52;
    int4 v[13];
    #pragma unroll
    for (int i = 0; i < 13; ++i) v[i] = ((const int4*)(deg + base))[i];
    int run = 0;
    #pragma unroll
    for (int i = 0; i < 13; ++i) {
        int a;
        a = v[i].x; v[i].x = run; run += a;
        a = v[i].y; v[i].y = run; run += a;
        a = v[i].z; v[i].z = run; run += a;
        a = v[i].w; v[i].w = run; run += a;
    }
    int sv = run;
    #pragma unroll
    for (int d = 1; d < 64; d <<= 1) {
        int t = __shfl_up(sv, d, 64);
        if (lane >= d) sv += t;
    }
    if (lane == 63) wsum[w] = sv;
    __syncthreads();
    if (tid < 16) {
        int t = wsum[tid];
        #pragma unroll
        for (int d = 1; d < 16; d <<= 1) {
            int u = __shfl_up(t, d, 64);
            if (tid >= d) t += u;
        }
        wsum[tid] = t;
    }
    __syncthreads();
    int off = (w ? wsum[w - 1] : 0) + (sv - run);
    #pragma unroll
    for (int i = 0; i < 13; ++i) {
        int4 o = make_int4(v[i].x + off, v[i].y + off, v[i].z + off, v[i].w + off);
        ((int4*)(row_start + base))[i] = o;
        ((int4*)(cursor + base))[i] = o;
    }
}

// ---------------- K4: scatter edges into CSR slots (4 edges/thread) --------
__global__ __launch_bounds__(256) void scatter_kernel(
    const int* __restrict__ src, const int* __restrict__ dst,
    int* __restrict__ cursor, int* __restrict__ csr, int E)
{
    int i = (blockIdx.x * 256 + threadIdx.x) * 4;
    if (i + 3 < E) {
        int4 sv = *(const int4*)(src + i);
        int4 dv = *(const int4*)(dst + i);
        int p0 = atomicAdd(&cursor[dv.x], 1); csr[p0] = sv.x;
        int p1 = atomicAdd(&cursor[dv.y], 1); csr[p1] = sv.y;
        int p2 = atomicAdd(&cursor[dv.z], 1); csr[p2] = sv.z;
        int p3 = atomicAdd(&cursor[dv.w], 1); csr[p3] = sv.w;
    } else {
        for (; i < E; ++i) {
            int p = atomicAdd(&cursor[dst[i]], 1);
            csr[p] = src[i];
        }
    }
}

// ---------------- K5: fused attention + aggregation + ELU + linear ----------
// One wave per node; 4 groups x 16 lanes; lane = 4 channels; 16 edges/iter.
__global__ __launch_bounds__(256) void gat_main(
    const unsigned short* __restrict__ xlb, const float* __restrict__ xr,
    const int* __restrict__ row_start, const int* __restrict__ row_end,
    const int* __restrict__ csr,
    const float* __restrict__ att, const float* __restrict__ bias_conv,
    const float* __restrict__ W_lin, const float* __restrict__ b_lin,
    float* __restrict__ out, int nN)
{
    __shared__ float WT[64 * 65];   // WT[c*65+o] = W_lin[o][c], +1 pad
    __shared__ float hbuf[4][64];
    int tid = threadIdx.x;
    for (int idx = tid; idx < 64 * 64; idx += 256) {
        int o = idx >> 6, c = idx & 63;
        WT[c * 65 + o] = W_lin[idx];
    }
    int lane = tid & 63, w = tid >> 6;
    int g = lane >> 4, gl = lane & 15;
    int node = blockIdx.x * 4 + w;
    bool active = node < nN;
    if (active) {
        const float4 att4 = *(const float4*)(att + gl * 4);
        const float4 xr4  = *(const float4*)(xr + (size_t)node * HID + gl * 4);
        float4 acc = make_float4(0.f, 0.f, 0.f, 0.f);
        float denom = 0.f;
        // self loop: group 0 only
        if (g == 0) {
            ushort4 us = *(const ushort4*)(xlb + (size_t)node * HID + gl * 4);
            float xsx = bf2f(us.x), xsy = bf2f(us.y), xsz = bf2f(us.z), xsw = bf2f(us.w);
            float tx = xsx + xr4.x, ty = xsy + xr4.y;
            float tz = xsz + xr4.z, tw = xsw + xr4.w;
            float r =          att4.x * (fmaxf(tx, 0.f) + NEG * fminf(tx, 0.f));
            r = fmaf(att4.y, fmaxf(ty, 0.f) + NEG * fminf(ty, 0.f), r);
            r = fmaf(att4.z, fmaxf(tz, 0.f) + NEG * fminf(tz, 0.f), r);
            r = fmaf(att4.w, fmaxf(tw, 0.f) + NEG * fminf(tw, 0.f), r);
            r += __shfl_xor(r, 1, 64);
            r += __shfl_xor(r, 2, 64);
            r += __shfl_xor(r, 4, 64);
            r += __shfl_xor(r, 8, 64);
            float ev = __expf(r);
            denom = ev;
            acc.x = ev * xsx; acc.y = ev * xsy;
            acc.z = ev * xsz; acc.w = ev * xsw;
        }
        int s0 = row_start[node], e0 = row_end[node];
        int last = e0 - 1;
        for (int base = s0; base < e0; base += 16) {
            int kb = base + g * 4;
            int k0 = (kb     <= last) ? kb     : last;
            int k1 = (kb + 1 <= last) ? kb + 1 : last;
            int k2 = (kb + 2 <= last) ? kb + 2 : last;
            int k3 = (kb + 3 <= last) ? kb + 3 : last;
            int j0 = csr[k0], j1 = csr[k1], j2 = csr[k2], j3 = csr[k3];
            ushort4 ua = *(const ushort4*)(xlb + (size_t)j0 * HID + gl * 4);
            ushort4 ub = *(const ushort4*)(xlb + (size_t)j1 * HID + gl * 4);
            ushort4 uc = *(const ushort4*)(xlb + (size_t)j2 * HID + gl * 4);
            ushort4 ud = *(const ushort4*)(xlb + (size_t)j3 * HID + gl * 4);
            float xax = bf2f(ua.x), xay = bf2f(ua.y), xaz = bf2f(ua.z), xaw = bf2f(ua.w);
            float xbx = bf2f(ub.x), xby = bf2f(ub.y), xbz = bf2f(ub.z), xbw = bf2f(ub.w);
            float xcx = bf2f(uc.x), xcy = bf2f(uc.y), xcz = bf2f(uc.z), xcw = bf2f(uc.w);
            float xdx = bf2f(ud.x), xdy = bf2f(ud.y), xdz = bf2f(ud.z), xdw = bf2f(ud.w);

            float t0, t1, t2, t3;
            float ra, rb, rc, rd;
            t0 = xax + xr4.x; t1 = xay + xr4.y; t2 = xaz + xr4.z; t3 = xaw + xr4.w;
            ra =          att4.x * (fmaxf(t0, 0.f) + NEG * fminf(t0, 0.f));
            ra = fmaf(att4.y, fmaxf(t1, 0.f) + NEG * fminf(t1, 0.f), ra);
            ra = fmaf(att4.z, fmaxf(t2, 0.f) + NEG * fminf(t2, 0.f), ra);
            ra = fmaf(att4.w, fmaxf(t3, 0.f) + NEG * fminf(t3, 0.f), ra);
            t0 = xbx + xr4.x; t1 = xby + xr4.y; t2 = xbz + xr4.z; t3 = xbw + xr4.w;
            rb =          att4.x * (fmaxf(t0, 0.f) + NEG * fminf(t0, 0.f));
            rb = fmaf(att4.y, fmaxf(t1, 0.f) + NEG * fminf(t1, 0.f), rb);
            rb = fmaf(att4.z, fmaxf(t2, 0.f) + NEG * fminf(t2, 0.f), rb);
            rb = fmaf(att4.w, fmaxf(t3, 0.f) + NEG * fminf(t3, 0.f), rb);
            t0 = xcx + xr4.x; t1 = xcy + xr4.y; t2 = xcz + xr4.z; t3 = xcw + xr4.w;
            rc =          att4.x * (fmaxf(t0, 0.f) + NEG * fminf(t0, 0.f));
            rc = fmaf(att4.y, fmaxf(t1, 0.f) + NEG * fminf(t1, 0.f), rc);
            rc = fmaf(att4.z, fmaxf(t2, 0.f) + NEG * fminf(t2, 0.f), rc);
            rc = fmaf(att4.w, fmaxf(t3, 0.f) + NEG * fminf(t3, 0.f), rc);
            t0 = xdx + xr4.x; t1 = xdy + xr4.y; t2 = xdz + xr4.z; t3 = xdw + xr4.w;
            rd =          att4.x * (fmaxf(t0, 0.f) + NEG * fminf(t0, 0.f));
            rd = fmaf(att4.y, fmaxf(t1, 0.f) + NEG * fminf(t1, 0.f), rd);
            rd = fmaf(att4.z, fmaxf(t2, 0.f) + NEG * fminf(t2, 0.f), rd);
            rd = fmaf(att4.w, fmaxf(t3, 0.f) + NEG * fminf(t3, 0.f), rd);

            ra += __shfl_xor(ra, 1, 64); rb += __shfl_xor(rb, 1, 64);
            rc += __shfl_xor(rc, 1, 64); rd += __shfl_xor(rd, 1, 64);
            ra += __shfl_xor(ra, 2, 64); rb += __shfl_xor(rb, 2, 64);
            rc += __shfl_xor(rc, 2, 64); rd += __shfl_xor(rd, 2, 64);
            ra += __shfl_xor(ra, 4, 64); rb += __shfl_xor(rb, 4, 64);
            rc += __shfl_xor(rc, 4, 64); rd += __shfl_xor(rd, 4, 64);
            ra += __shfl_xor(ra, 8, 64); rb += __shfl_xor(rb, 8, 64);
            rc += __shfl_xor(rc, 8, 64); rd += __shfl_xor(rd, 8, 64);

            float ea = (kb     < e0) ? __expf(ra) : 0.f;
            float eb = (kb + 1 < e0) ? __expf(rb) : 0.f;
            float ec = (kb + 2 < e0) ? __expf(rc) : 0.f;
            float ed = (kb + 3 < e0) ? __expf(rd) : 0.f;
            denom += (ea + eb) + (ec + ed);
            acc.x = fmaf(ea, xax, acc.x); acc.x = fmaf(eb, xbx, acc.x);
            acc.x = fmaf(ec, xcx, acc.x); acc.x = fmaf(ed, xdx, acc.x);
            acc.y = fmaf(ea, xay, acc.y); acc.y = fmaf(eb, xby, acc.y);
            acc.y = fmaf(ec, xcy, acc.y); acc.y = fmaf(ed, xdy, acc.y);
            acc.z = fmaf(ea, xaz, acc.z); acc.z = fmaf(eb, xbz, acc.z);
            acc.z = fmaf(ec, xcz, acc.z); acc.z = fmaf(ed, xdz, acc.z);
            acc.w = fmaf(ea, xaw, acc.w); acc.w = fmaf(eb, xbw, acc.w);
            acc.w = fmaf(ec, xcw, acc.w); acc.w = fmaf(ed, xdw, acc.w);
        }
        denom += __shfl_xor(denom, 16, 64);
        denom += __shfl_xor(denom, 32, 64);
        acc.x += __shfl_xor(acc.x, 16, 64); acc.x += __shfl_xor(acc.x, 32, 64);
        acc.y += __shfl_xor(acc.y, 16, 64); acc.y += __shfl_xor(acc.y, 32, 64);
        acc.z += __shfl_xor(acc.z, 16, 64); acc.z += __shfl_xor(acc.z, 32, 64);
        acc.w += __shfl_xor(acc.w, 16, 64); acc.w += __shfl_xor(acc.w, 32, 64);
        float inv = 1.f / (denom + 1e-16f);
        float4 b4 = *(const float4*)(bias_conv + gl * 4);
        float hx = fmaf(acc.x, inv, b4.x);
        float hy = fmaf(acc.y, inv, b4.y);
        float hz = fmaf(acc.z, inv, b4.z);
        float hw = fmaf(acc.w, inv, b4.w);
        hx = (hx > 0.f) ? hx : (__expf(hx) - 1.f);
        hy = (hy > 0.f) ? hy : (__expf(hy) - 1.f);
        hz = (hz > 0.f) ? hz : (__expf(hz) - 1.f);
        hw = (hw > 0.f) ? hw : (__expf(hw) - 1.f);
        if (g == 0) {
            *(float4*)(&hbuf[w][gl * 4]) = make_float4(hx, hy, hz, hw);
        }
    }
    __syncthreads();
    if (active) {
        float y = b_lin[lane];
        #pragma unroll 8
        for (int c = 0; c < 64; ++c)
            y = fmaf(WT[c * 65 + lane], hbuf[w][c], y);
        out[(size_t)node * 64 + lane] = y;
    }
}

extern "C" void kernel_launch(void* const* d_in, const int* in_sizes, int n_in,
                              void* d_out, int out_size, void* d_ws, size_t ws_size,
                              hipStream_t stream) {
    const float* x      = (const float*)d_in[0];
    const int*   ei     = (const int*)d_in[1];
    // d_in[2] = edge_weight: unused by the reference
    const float* W_l    = (const float*)d_in[3];
    const float* W_r    = (const float*)d_in[4];
    const float* att    = (const float*)d_in[5];
    const float* bias_c = (const float*)d_in[6];
    const float* W_lin  = (const float*)d_in[7];
    const float* b_lin  = (const float*)d_in[8];
    float* out = (float*)d_out;

    int N = in_sizes[0] / IN_CH;
    int E = in_sizes[2];
    const int* srcp = ei;
    const int* dstp = ei + E;

    int NP = 53248;   // 1024 * 52, >= N, int4-aligned per thread

    char* ws = (char*)d_ws;
    float* xr = (float*)ws;                                   // N*64 f32
    unsigned short* xlb = (unsigned short*)(xr + (size_t)N * HID);  // N*64 bf16
    int* deg       = (int*)(xlb + (size_t)N * HID);
    int* row_start = deg + NP;
    int* cursor    = row_start + NP;
    int* csr       = cursor + NP;

    hipMemsetAsync(deg, 0, (size_t)NP * sizeof(int), stream);
    proj_kernel<<<(N + 63) / 64, 512, 0, stream>>>(x, W_l, W_r, xlb, xr,
                                                   dstp, deg, N, E);
    scan_kernel<<<1, 1024, 0, stream>>>(deg, row_start, cursor, NP);
    scatter_kernel<<<(E / 4 + 255) / 256, 256, 0, stream>>>(srcp, dstp, cursor, csr, E);
    gat_main<<<(N + 3) / 4, 256, 0, stream>>>(xlb, xr, row_start, cursor, csr,
                                              att, bias_c, W_lin, b_lin, out, N);
}